// Round 19
// baseline (263.412 us; speedup 1.0000x reference)
//
#include <hip/hip_runtime.h>
#include <hip/hip_bf16.h>
#include <math.h>

#define EMBED 256
#define NF 3
#define DD 64
#define BM 128
#define BN 128
#define BKF 128   // fp8 K-elements per LDS tile
#define MOTIF_BLOCKS 2048

typedef unsigned short ushort_t;
typedef unsigned char uchar_t;
typedef float f32x4 __attribute__((ext_vector_type(4)));
typedef float f32x2 __attribute__((ext_vector_type(2)));

__device__ __forceinline__ void gl2lds16(const void* g, void* l) {
    __builtin_amdgcn_global_load_lds(
        (const __attribute__((address_space(1))) unsigned int*)g,
        (__attribute__((address_space(3))) unsigned int*)l, 16, 0, 0);
}

__device__ __forceinline__ uchar_t f2fp8(float f) {
    int p = __builtin_amdgcn_cvt_pk_fp8_f32(f, f, 0, false);  // e4m3 OCP on gfx950
    return (uchar_t)(p & 0xff);
}
template<bool HI>
__device__ __forceinline__ f32x2 pk2(unsigned int w) {
    return __builtin_amdgcn_cvt_pk_f32_fp8((int)w, HI);       // .x = low byte
}

// ---------------- Kernel 1: normalize + random_mapping (grid-stride) --------
__global__ __launch_bounds__(256) void k_embed(
    const float* __restrict__ x,
    const float* __restrict__ feats,
    const float* __restrict__ feat_free,
    const float* __restrict__ ks,
    const float* __restrict__ Ws,
    const float* __restrict__ bias,
    const float* __restrict__ W_free,
    const float* __restrict__ b_free,
    float* __restrict__ p_out,        // [3][N][32]
    uchar_t* __restrict__ xnf8,       // [Npad][256] fp8 (normalized x, PRE-SCALED by 5)
    uchar_t* __restrict__ x2nf8,      // [Npad][256] fp8 (normalized x2)
    float* __restrict__ zero_base,    // rowsum|colsum|acc3, 2N+3 floats
    int N, int Npad)
{
    int tid  = threadIdx.x;
    int wave = tid >> 6;
    int t    = tid & 63;
    int gtid = blockIdx.x * 256 + tid;
    int stride = gridDim.x * 256;

    for (int i = gtid; i < 2*N + 3; i += stride) zero_base[i] = 0.f;
    {
        int pad = (Npad - N) * (EMBED/4);
        int* pa = (int*)(xnf8  + (size_t)N*EMBED);
        int* pb = (int*)(x2nf8 + (size_t)N*EMBED);
        for (int i = gtid; i < pad; i += stride) { pa[i] = 0; pb[i] = 0; }
    }

    __shared__ float Wl[128*65];      // rows: [i*32+c] for Ws, [96+c] for W_free
    __shared__ float xi_s[4][NF][32];
    __shared__ float ff_s[4][32];

    for (int e = tid; e < NF*DD*32; e += 256) {
        int i = e >> 11, rem = e & 2047, tr = rem >> 5, c = rem & 31;
        Wl[(i*32 + c)*65 + tr] = Ws[e];
    }
    for (int e = tid; e < DD*32; e += 256) {
        int tr = e >> 5, c = e & 31;
        Wl[(96 + c)*65 + tr] = W_free[e];
    }
    __syncthreads();                   // Wl ready; no barriers needed below

    float (*xi)[32] = xi_s[wave];
    float* ffs = ff_s[wave];
    int ngroups = (N + 3) >> 2;

    for (int grp = blockIdx.x; grp < ngroups; grp += gridDim.x) {
        int n = grp*4 + wave;
        if (n >= N) continue;          // wave-uniform

        float v[NF];
        float ffv = 0.f;
        if (t < 32) {
            #pragma unroll
            for (int i = 0; i < NF; ++i) v[i] = feats[((size_t)i*N + n)*32 + t];
            ffv = feat_free[(size_t)n*32 + t];
        } else {
            #pragma unroll
            for (int i = 0; i < NF; ++i) v[i] = 0.f;
        }

        float num[NF];
        #pragma unroll
        for (int i = 0; i < NF; ++i) {
            float s = v[i]*v[i];
            s += __shfl_xor(s, 1, 64);  s += __shfl_xor(s, 2, 64);
            s += __shfl_xor(s, 4, 64);  s += __shfl_xor(s, 8, 64);
            s += __shfl_xor(s, 16, 64);
            s = __shfl(s, 0, 64);
            float k = ks[i];
            float scale = 0.45f / (sqrtf(s) * sqrtf(fabsf(k)));
            float xv = v[i] * scale;
            if (t < 32) {
                xi[i][t] = xv;                       // wave-local LDS (lgkmcnt ordering)
                p_out[((size_t)i*N + n)*32 + t] = xv;
            }
            num[i] = 1.0f + k * (scale*scale*s);
        }
        if (t < 32) ffs[t] = ffv;

        float z[4];
        float zsq = 0.f;
        #pragma unroll
        for (int i = 0; i < NF; ++i) {
            float div = 0.f;
            #pragma unroll
            for (int c = 0; c < 32; ++c) {
                float d = xi[i][c] - Wl[(i*32 + c)*65 + t];
                div += d*d;
            }
            float dist = __logf(num[i] / (div + 1e-5f));
            float zz = __expf(15.5f * dist) * __cosf(dist + bias[i*DD + t]);
            z[i] = zz;
            zsq += zz*zz;
        }
        {
            float dot = 0.f;
            #pragma unroll
            for (int c = 0; c < 32; ++c) dot = fmaf(ffs[c], Wl[(96 + c)*65 + t], dot);
            float zz = __expf(15.5f * dot) * __cosf(dot + b_free[t]);
            z[3] = zz;
            zsq += zz*zz;
        }
        zsq += __shfl_xor(zsq, 1, 64);  zsq += __shfl_xor(zsq, 2, 64);
        zsq += __shfl_xor(zsq, 4, 64);  zsq += __shfl_xor(zsq, 8, 64);
        zsq += __shfl_xor(zsq, 16, 64); zsq += __shfl_xor(zsq, 32, 64);
        float iv2 = 1.0f / sqrtf(zsq);

        #pragma unroll
        for (int i = 0; i < NF; ++i) x2nf8[(size_t)n*EMBED + i*DD + t] = f2fp8(z[i]*iv2);
        x2nf8[(size_t)n*EMBED + 192 + t] = f2fp8(z[3]*iv2);

        float xv[4];
        float s1 = 0.f;
        #pragma unroll
        for (int q = 0; q < 4; ++q) { xv[q] = x[(size_t)n*EMBED + q*64 + t]; s1 += xv[q]*xv[q]; }
        s1 += __shfl_xor(s1, 1, 64);  s1 += __shfl_xor(s1, 2, 64);
        s1 += __shfl_xor(s1, 4, 64);  s1 += __shfl_xor(s1, 8, 64);
        s1 += __shfl_xor(s1, 16, 64); s1 += __shfl_xor(s1, 32, 64);
        float iv1 = 5.0f / sqrtf(s1);          // pre-scale by 5 (1/TEMP)
        #pragma unroll
        for (int q = 0; q < 4; ++q) xnf8[(size_t)n*EMBED + q*64 + t] = f2fp8(xv[q]*iv1);
    }
}

// ---------------- Kernel 2: per-node MLP hidden partials -> fp8 H -----------
__global__ __launch_bounds__(256) void k_mlp1(
    const float* __restrict__ p,          // [3][N][32]
    const float* __restrict__ feat_free,  // [N][32]
    const float* __restrict__ W1,         // [96][64]
    const float* __restrict__ b1,         // [64]
    uchar_t* __restrict__ H,              // [4][3][N][64] fp8
    int N)
{
    int lane = threadIdx.x & 63;
    int gw = (blockIdx.x * blockDim.x + threadIdx.x) >> 6;
    int nwaves = (gridDim.x * blockDim.x) >> 6;

    float wcol[96];
    #pragma unroll
    for (int c = 0; c < 96; ++c) wcol[c] = W1[c*64 + lane];
    float b1l = b1[lane];

    int total = 4 * N;
    for (int unit = gw; unit < total; unit += nwaves) {
        int node = __builtin_amdgcn_readfirstlane(unit >> 2);
        int prod = __builtin_amdgcn_readfirstlane(unit & 3);
        const float* P = (prod < 3) ? (p + ((size_t)prod*N + node)*32)
                                    : (feat_free + (size_t)node*32);
        float fc[32];
        #pragma unroll
        for (int c = 0; c < 32; ++c) fc[c] = P[c];
        #pragma unroll
        for (int s = 0; s < 3; ++s) {
            float h = (s == 2) ? b1l : 0.f;
            #pragma unroll
            for (int c = 0; c < 32; ++c) h = fmaf(fc[c], wcol[s*32 + c], h);
            H[(((size_t)prod*3 + s)*N + node)*64 + lane] = f2fp8(h);
        }
    }
}

// ---------------- Kernel 3: FUSED motif + GEMM, Bresenham-interleaved -------
// isMotif(b) = floor((b+1)R) > floor(bR), R = MOTIF_BLOCKS/total: motif blocks
// appear every ~4.05 blockIdx -> spread over all XCDs; each CU co-hosts
// ~1 motif (latency-bound gather) + ~3 sim (MFMA/barrier) blocks.
__global__ __launch_bounds__(256) void k_fused(
    const uchar_t* __restrict__ xn, const uchar_t* __restrict__ x2n,
    const uchar_t* __restrict__ H,        // [4][3][N][64] fp8
    const int* __restrict__ motif,        // [3][M]
    const int* __restrict__ neg_uv,       // [2][M]
    const float* __restrict__ W2,
    const float* __restrict__ b2,
    float* __restrict__ rowsum, float* __restrict__ colsum, float* __restrict__ pos,
    float* __restrict__ partials,         // [MOTIF_BLOCKS]
    int N, int nb, int M, int total_blocks)
{
    __shared__ __align__(16) uchar_t smem[BM*BKF + BN*BKF + 1024];

    int b = blockIdx.x;
    int mlo = (int)(((long)b     * MOTIF_BLOCKS) / total_blocks);
    int mhi = (int)(((long)(b+1) * MOTIF_BLOCKS) / total_blocks);

    if (mhi > mlo) {
        // ---------------- motif path (virtual id = mlo) ----------------
        float* wred = (float*)smem;
        int mid  = mlo;
        int lane = threadIdx.x & 63;
        int sub  = lane >> 3;
        int ch   = (lane & 7) * 8;
        int caseId = mid & 7;
        int rank   = (mid >> 3) * 4 + (threadIdx.x >> 6);   // 0..1023
        int prod  = caseId >> 1;
        int isneg = caseId & 1;
        const uchar_t* Hu = H + ((size_t)prod*3 + 0)*N*64;
        const uchar_t* Hv = H + ((size_t)prod*3 + 1)*N*64;
        const uchar_t* Hw = H + ((size_t)prod*3 + 2)*N*64;
        const int* iu = isneg ? neg_uv       : motif;
        const int* iv = isneg ? (neg_uv + M) : (motif + M);
        const int* iw = motif + 2*M;

        float w2c[8];
        #pragma unroll
        for (int c = 0; c < 8; ++c) w2c[c] = W2[ch + c];
        float b2v = b2[0];

        float accl = 0.f;
        #pragma unroll 2
        for (int r0 = rank*8; r0 < M; r0 += 8192) {
            int r = r0 + sub;
            bool ok = (r < M);
            int rc = ok ? r : 0;
            int u = iu[rc], v = iv[rc], w = iw[rc];
            uint2 du = *(const uint2*)&Hu[(size_t)u*64 + ch];
            uint2 dv = *(const uint2*)&Hv[(size_t)v*64 + ch];
            uint2 dw = *(const uint2*)&Hw[(size_t)w*64 + ch];
            float pl = 0.f;
            {
                f32x2 s;
                s = pk2<false>(du.x) + pk2<false>(dv.x) + pk2<false>(dw.x);
                pl = fmaf(fmaxf(s.x,0.f), w2c[0], pl);  pl = fmaf(fmaxf(s.y,0.f), w2c[1], pl);
                s = pk2<true>(du.x) + pk2<true>(dv.x) + pk2<true>(dw.x);
                pl = fmaf(fmaxf(s.x,0.f), w2c[2], pl);  pl = fmaf(fmaxf(s.y,0.f), w2c[3], pl);
                s = pk2<false>(du.y) + pk2<false>(dv.y) + pk2<false>(dw.y);
                pl = fmaf(fmaxf(s.x,0.f), w2c[4], pl);  pl = fmaf(fmaxf(s.y,0.f), w2c[5], pl);
                s = pk2<true>(du.y) + pk2<true>(dv.y) + pk2<true>(dw.y);
                pl = fmaf(fmaxf(s.x,0.f), w2c[6], pl);  pl = fmaf(fmaxf(s.y,0.f), w2c[7], pl);
            }
            pl += __shfl_xor(pl, 1, 64);
            pl += __shfl_xor(pl, 2, 64);
            pl += __shfl_xor(pl, 4, 64);
            float logit = pl + b2v;
            float z = isneg ? -logit : logit;
            float sp = fmaxf(-z, 0.f) + __logf(1.f + __expf(-fabsf(z)));
            accl -= ok ? sp : 0.f;
        }
        #pragma unroll
        for (int m = 1; m < 64; m <<= 1) accl += __shfl_xor(accl, m, 64);

        if (lane == 0) wred[threadIdx.x >> 6] = accl;
        __syncthreads();
        if (threadIdx.x == 0)
            partials[mid] = (wred[0] + wred[1] + wred[2] + wred[3]) * 0.125f;
        return;
    }

    // ---------------- sim path ----------------
    uchar_t* As = smem;
    uchar_t* Bs = smem + BM*BKF;
    float* rsum_s = (float*)(smem + BM*BKF + BN*BKF);
    float* csum_s = rsum_s + BM;

    int tid  = threadIdx.x;
    int lane = tid & 63;
    int w    = tid >> 6;
    int wr   = w >> 1, wc = w & 1;
    int quad = lane >> 4, l15 = lane & 15;

    int pid = b - mhi;                 // b minus motif blocks before/at b
    int per_group = 8 * nb;
    int group = pid / per_group;
    int rem = pid - group * per_group;
    int rowspan = min(8, nb - group * 8);
    int prow = group * 8 + rem % rowspan;
    int pcol = rem / rowspan;
    int row0 = prow * BM, col0 = pcol * BN;

    if (tid < BM) { rsum_s[tid] = 0.f; csum_s[tid] = 0.f; }

    f32x4 acc[4][4];
    #pragma unroll
    for (int i = 0; i < 4; ++i)
        #pragma unroll
        for (int j = 0; j < 4; ++j) acc[i][j] = (f32x4){0.f,0.f,0.f,0.f};

    for (int kt = 0; kt < EMBED; kt += BKF) {
        #pragma unroll
        for (int i = 0; i < 4; ++i) {
            int slot = i*256 + tid;          // slot = row*8 + chunk
            int r = slot >> 3, c = slot & 7;
            int sc = c ^ (r & 7);
            gl2lds16(xn  + (size_t)(row0 + r)*EMBED + kt + sc*16, &As[slot*16]);
            gl2lds16(x2n + (size_t)(col0 + r)*EMBED + kt + sc*16, &Bs[slot*16]);
        }
        __syncthreads();
        #pragma unroll
        for (int s = 0; s < 4; ++s) {        // 4 k-steps of K=32
            long a[4], bb[4];
            int g = s*2 + (quad >> 1);
            int sub8 = (quad & 1) * 8;
            #pragma unroll
            for (int ti = 0; ti < 4; ++ti) {
                int ra = wr*64 + ti*16 + l15;
                a[ti] = *(const long*)&As[ra*BKF + (g ^ (ra & 7))*16 + sub8];
            }
            #pragma unroll
            for (int tj = 0; tj < 4; ++tj) {
                int rb = wc*64 + tj*16 + l15;
                bb[tj] = *(const long*)&Bs[rb*BKF + (g ^ (rb & 7))*16 + sub8];
            }
            #pragma unroll
            for (int ti = 0; ti < 4; ++ti)
                #pragma unroll
                for (int tj = 0; tj < 4; ++tj)
                    acc[ti][tj] = __builtin_amdgcn_mfma_f32_16x16x32_fp8_fp8(a[ti], bb[tj], acc[ti][tj], 0, 0, 0);
        }
        __syncthreads();
    }

    // epilogue: e = exp(acc) (operands pre-scaled by 5), diag, row/col partials
    #pragma unroll
    for (int ti = 0; ti < 4; ++ti) {
        #pragma unroll
        for (int tj = 0; tj < 4; ++tj) {
            #pragma unroll
            for (int r = 0; r < 4; ++r) {
                int gi = row0 + wr*64 + ti*16 + quad*4 + r;
                int gj = col0 + wc*64 + tj*16 + l15;
                float e = 0.f;
                if (gi < N && gj < N) {
                    e = __expf(acc[ti][tj][r]);
                    if (gi == gj) pos[gi] = e;
                }
                acc[ti][tj][r] = e;
            }
        }
    }
    #pragma unroll
    for (int ti = 0; ti < 4; ++ti) {
        #pragma unroll
        for (int r = 0; r < 4; ++r) {
            float rsv = acc[ti][0][r] + acc[ti][1][r] + acc[ti][2][r] + acc[ti][3][r];
            rsv += __shfl_xor(rsv, 1, 64);
            rsv += __shfl_xor(rsv, 2, 64);
            rsv += __shfl_xor(rsv, 4, 64);
            rsv += __shfl_xor(rsv, 8, 64);
            if (l15 == 0) atomicAdd(&rsum_s[wr*64 + ti*16 + quad*4 + r], rsv);
        }
    }
    #pragma unroll
    for (int tj = 0; tj < 4; ++tj) {
        float csv = 0.f;
        #pragma unroll
        for (int ti = 0; ti < 4; ++ti)
            #pragma unroll
            for (int r = 0; r < 4; ++r) csv += acc[ti][tj][r];
        csv += __shfl_xor(csv, 16, 64);
        csv += __shfl_xor(csv, 32, 64);
        if (lane < 16) atomicAdd(&csum_s[wc*64 + tj*16 + lane], csv);
    }
    __syncthreads();
    if (tid < BM) {
        int gi = row0 + tid;
        if (gi < N) atomicAdd(&rowsum[gi], rsum_s[tid]);
        int gj = col0 + tid;
        if (gj < N) atomicAdd(&colsum[gj], csum_s[tid]);
    }
}

// ---------------- Kernel 4a: parallel log-reduction ------------------------
__global__ __launch_bounds__(256) void k_final1(
    const float* __restrict__ rowsum, const float* __restrict__ colsum,
    const float* __restrict__ pos, const float* __restrict__ partials,
    float* __restrict__ acc3, int N, int nparts)
{
    __shared__ float red1[256], red2[256], red3[256];
    int t = threadIdx.x;
    int g = blockIdx.x * 256 + t;
    int stride = gridDim.x * 256;
    float l1 = 0.f, l2 = 0.f, mo = 0.f;
    for (int i = g; i < N; i += stride) {
        float pv = pos[i];
        l1 += __logf((colsum[i] - pv) / pv);
        l2 += __logf((rowsum[i] - pv) / pv);
    }
    for (int i = g; i < nparts; i += stride) mo += partials[i];
    red1[t] = l1; red2[t] = l2; red3[t] = mo; __syncthreads();
    for (int s = 128; s > 0; s >>= 1) {
        if (t < s) { red1[t] += red1[t+s]; red2[t] += red2[t+s]; red3[t] += red3[t+s]; }
        __syncthreads();
    }
    if (t == 0) {
        atomicAdd(&acc3[0], red1[0]);
        atomicAdd(&acc3[1], red2[0]);
        atomicAdd(&acc3[2], red3[0]);
    }
}

// ---------------- Kernel 4b: finalize ---------------------------------------
__global__ void k_final2(const float* __restrict__ acc3,
                         float* __restrict__ out, int N, int M)
{
    if (threadIdx.x == 0) {
        float cl = 0.5f * (acc3[0] + acc3[1]) / (float)N;
        out[0] = cl - acc3[2] / (float)M;
    }
}

extern "C" void kernel_launch(void* const* d_in, const int* in_sizes, int n_in,
                              void* d_out, int out_size, void* d_ws, size_t ws_size,
                              hipStream_t stream)
{
    const float* x         = (const float*)d_in[0];
    const float* feats     = (const float*)d_in[1];
    const float* feat_free = (const float*)d_in[2];
    const float* ks        = (const float*)d_in[3];
    const float* Ws        = (const float*)d_in[4];
    const float* bias      = (const float*)d_in[5];
    const float* W_free    = (const float*)d_in[6];
    const float* b_free    = (const float*)d_in[7];
    const float* W1        = (const float*)d_in[8];
    const float* b1        = (const float*)d_in[9];
    const float* W2        = (const float*)d_in[10];
    const float* b2        = (const float*)d_in[11];
    const int*   motif     = (const int*)d_in[12];
    const int*   neg_uv    = (const int*)d_in[13];
    int N = in_sizes[0] / EMBED;          // 10000
    int M = in_sizes[13] / 2;             // 50000
    int nb = (N + BM - 1) / BM;           // 79
    int Npad = nb * BM;                   // 10112
    int total_blocks = MOTIF_BLOCKS + nb*nb;   // 8289

    uchar_t* xnf8  = (uchar_t*)d_ws;                       // Npad*256 fp8
    uchar_t* x2nf8 = xnf8 + (size_t)Npad*EMBED;            // Npad*256 fp8
    uchar_t* H8    = x2nf8 + (size_t)Npad*EMBED;           // 12*N*64 fp8
    float* p      = (float*)(H8 + (size_t)12*N*64);        // 3*N*32
    float* posv   = p + (size_t)3*N*32;                    // N
    float* rowsum = posv + N;                              // N
    float* colsum = rowsum + N;                            // N
    float* acc3   = colsum + N;                            // 3 (zeroed w/ rowsum/colsum)
    float* partials = acc3 + 3;                            // MOTIF_BLOCKS

    k_embed<<<512, 256, 0, stream>>>(x, feats, feat_free, ks, Ws, bias,
                                     W_free, b_free, p, xnf8, x2nf8,
                                     rowsum, N, Npad);
    k_mlp1<<<1024, 256, 0, stream>>>(p, feat_free, W1, b1, H8, N);
    k_fused<<<total_blocks, 256, 0, stream>>>(xnf8, x2nf8, H8, motif, neg_uv,
                                              W2, b2, rowsum, colsum, posv,
                                              partials, N, nb, M, total_blocks);
    k_final1<<<64, 256, 0, stream>>>(rowsum, colsum, posv, partials, acc3, N, MOTIF_BLOCKS);
    k_final2<<<1, 64, 0, stream>>>(acc3, (float*)d_out, N, M);
}

// Round 20
// 228.556 us; speedup vs baseline: 1.1525x; 1.1525x over previous
//
#include <hip/hip_runtime.h>
#include <hip/hip_bf16.h>
#include <math.h>

#define EMBED 256
#define NF 3
#define DD 64
#define BM 128
#define BN 128
#define BKF 128   // fp8 K-elements per LDS tile
#define MOTIF_BLOCKS 2048

typedef unsigned short ushort_t;
typedef unsigned char uchar_t;
typedef float f32x4 __attribute__((ext_vector_type(4)));
typedef float f32x2 __attribute__((ext_vector_type(2)));

__device__ __forceinline__ void gl2lds16(const void* g, void* l) {
    __builtin_amdgcn_global_load_lds(
        (const __attribute__((address_space(1))) unsigned int*)g,
        (__attribute__((address_space(3))) unsigned int*)l, 16, 0, 0);
}

__device__ __forceinline__ uchar_t f2fp8(float f) {
    int p = __builtin_amdgcn_cvt_pk_fp8_f32(f, f, 0, false);  // e4m3 OCP on gfx950
    return (uchar_t)(p & 0xff);
}
template<bool HI>
__device__ __forceinline__ f32x2 pk2(unsigned int w) {
    return __builtin_amdgcn_cvt_pk_f32_fp8((int)w, HI);       // .x = low byte
}

// ---------------- Kernel 1: normalize + random_mapping (grid-stride) --------
__global__ __launch_bounds__(256) void k_embed(
    const float* __restrict__ x,
    const float* __restrict__ feats,
    const float* __restrict__ feat_free,
    const float* __restrict__ ks,
    const float* __restrict__ Ws,
    const float* __restrict__ bias,
    const float* __restrict__ W_free,
    const float* __restrict__ b_free,
    float* __restrict__ p_out,        // [3][N][32]
    uchar_t* __restrict__ xnf8,       // [Npad][256] fp8 (normalized x, PRE-SCALED by 5)
    uchar_t* __restrict__ x2nf8,      // [Npad][256] fp8 (normalized x2)
    float* __restrict__ zero_base,    // rowsum|colsum|acc3, 2N+3 floats
    int N, int Npad)
{
    int tid  = threadIdx.x;
    int wave = tid >> 6;
    int t    = tid & 63;
    int gtid = blockIdx.x * 256 + tid;
    int stride = gridDim.x * 256;

    for (int i = gtid; i < 2*N + 3; i += stride) zero_base[i] = 0.f;
    {
        int pad = (Npad - N) * (EMBED/4);
        int* pa = (int*)(xnf8  + (size_t)N*EMBED);
        int* pb = (int*)(x2nf8 + (size_t)N*EMBED);
        for (int i = gtid; i < pad; i += stride) { pa[i] = 0; pb[i] = 0; }
    }

    __shared__ float Wl[128*65];      // rows: [i*32+c] for Ws, [96+c] for W_free
    __shared__ float xi_s[4][NF][32];
    __shared__ float ff_s[4][32];

    for (int e = tid; e < NF*DD*32; e += 256) {
        int i = e >> 11, rem = e & 2047, tr = rem >> 5, c = rem & 31;
        Wl[(i*32 + c)*65 + tr] = Ws[e];
    }
    for (int e = tid; e < DD*32; e += 256) {
        int tr = e >> 5, c = e & 31;
        Wl[(96 + c)*65 + tr] = W_free[e];
    }
    __syncthreads();                   // Wl ready; no barriers needed below

    float (*xi)[32] = xi_s[wave];
    float* ffs = ff_s[wave];
    int ngroups = (N + 3) >> 2;

    for (int grp = blockIdx.x; grp < ngroups; grp += gridDim.x) {
        int n = grp*4 + wave;
        if (n >= N) continue;          // wave-uniform

        float v[NF];
        float ffv = 0.f;
        if (t < 32) {
            #pragma unroll
            for (int i = 0; i < NF; ++i) v[i] = feats[((size_t)i*N + n)*32 + t];
            ffv = feat_free[(size_t)n*32 + t];
        } else {
            #pragma unroll
            for (int i = 0; i < NF; ++i) v[i] = 0.f;
        }

        float num[NF];
        #pragma unroll
        for (int i = 0; i < NF; ++i) {
            float s = v[i]*v[i];
            s += __shfl_xor(s, 1, 64);  s += __shfl_xor(s, 2, 64);
            s += __shfl_xor(s, 4, 64);  s += __shfl_xor(s, 8, 64);
            s += __shfl_xor(s, 16, 64);
            s = __shfl(s, 0, 64);
            float k = ks[i];
            float scale = 0.45f / (sqrtf(s) * sqrtf(fabsf(k)));
            float xv = v[i] * scale;
            if (t < 32) {
                xi[i][t] = xv;                       // wave-local LDS (lgkmcnt ordering)
                p_out[((size_t)i*N + n)*32 + t] = xv;
            }
            num[i] = 1.0f + k * (scale*scale*s);
        }
        if (t < 32) ffs[t] = ffv;

        float z[4];
        float zsq = 0.f;
        #pragma unroll
        for (int i = 0; i < NF; ++i) {
            float div = 0.f;
            #pragma unroll
            for (int c = 0; c < 32; ++c) {
                float d = xi[i][c] - Wl[(i*32 + c)*65 + t];
                div += d*d;
            }
            float dist = __logf(num[i] / (div + 1e-5f));
            float zz = __expf(15.5f * dist) * __cosf(dist + bias[i*DD + t]);
            z[i] = zz;
            zsq += zz*zz;
        }
        {
            float dot = 0.f;
            #pragma unroll
            for (int c = 0; c < 32; ++c) dot = fmaf(ffs[c], Wl[(96 + c)*65 + t], dot);
            float zz = __expf(15.5f * dot) * __cosf(dot + b_free[t]);
            z[3] = zz;
            zsq += zz*zz;
        }
        zsq += __shfl_xor(zsq, 1, 64);  zsq += __shfl_xor(zsq, 2, 64);
        zsq += __shfl_xor(zsq, 4, 64);  zsq += __shfl_xor(zsq, 8, 64);
        zsq += __shfl_xor(zsq, 16, 64); zsq += __shfl_xor(zsq, 32, 64);
        float iv2 = 1.0f / sqrtf(zsq);

        #pragma unroll
        for (int i = 0; i < NF; ++i) x2nf8[(size_t)n*EMBED + i*DD + t] = f2fp8(z[i]*iv2);
        x2nf8[(size_t)n*EMBED + 192 + t] = f2fp8(z[3]*iv2);

        float xv[4];
        float s1 = 0.f;
        #pragma unroll
        for (int q = 0; q < 4; ++q) { xv[q] = x[(size_t)n*EMBED + q*64 + t]; s1 += xv[q]*xv[q]; }
        s1 += __shfl_xor(s1, 1, 64);  s1 += __shfl_xor(s1, 2, 64);
        s1 += __shfl_xor(s1, 4, 64);  s1 += __shfl_xor(s1, 8, 64);
        s1 += __shfl_xor(s1, 16, 64); s1 += __shfl_xor(s1, 32, 64);
        float iv1 = 5.0f / sqrtf(s1);          // pre-scale by 5 (1/TEMP)
        #pragma unroll
        for (int q = 0; q < 4; ++q) xnf8[(size_t)n*EMBED + q*64 + t] = f2fp8(xv[q]*iv1);
    }
}

// ---------------- Kernel 2: per-node MLP hidden partials -> fp8 H -----------
__global__ __launch_bounds__(256) void k_mlp1(
    const float* __restrict__ p,          // [3][N][32]
    const float* __restrict__ feat_free,  // [N][32]
    const float* __restrict__ W1,         // [96][64]
    const float* __restrict__ b1,         // [64]
    uchar_t* __restrict__ H,              // [4][3][N][64] fp8
    int N)
{
    int lane = threadIdx.x & 63;
    int gw = (blockIdx.x * blockDim.x + threadIdx.x) >> 6;
    int nwaves = (gridDim.x * blockDim.x) >> 6;

    float wcol[96];
    #pragma unroll
    for (int c = 0; c < 96; ++c) wcol[c] = W1[c*64 + lane];
    float b1l = b1[lane];

    int total = 4 * N;
    for (int unit = gw; unit < total; unit += nwaves) {
        int node = __builtin_amdgcn_readfirstlane(unit >> 2);
        int prod = __builtin_amdgcn_readfirstlane(unit & 3);
        const float* P = (prod < 3) ? (p + ((size_t)prod*N + node)*32)
                                    : (feat_free + (size_t)node*32);
        float fc[32];
        #pragma unroll
        for (int c = 0; c < 32; ++c) fc[c] = P[c];
        #pragma unroll
        for (int s = 0; s < 3; ++s) {
            float h = (s == 2) ? b1l : 0.f;
            #pragma unroll
            for (int c = 0; c < 32; ++c) h = fmaf(fc[c], wcol[s*32 + c], h);
            H[(((size_t)prod*3 + s)*N + node)*64 + lane] = f2fp8(h);
        }
    }
}

// ---------------- Kernel 3: FUSED motif + GEMM (r18 order, 32KB LDS) --------
// LDS is exactly As+Bs = 32768B: the epilogue reduce arrays ALIAS into As
// (dead after the K-loop) -> 163840/32768 = 5 blocks/CU (was 4 at 33792B).
__global__ __launch_bounds__(256, 5) void k_fused(
    const uchar_t* __restrict__ xn, const uchar_t* __restrict__ x2n,
    const uchar_t* __restrict__ H,        // [4][3][N][64] fp8
    const int* __restrict__ motif,        // [3][M]
    const int* __restrict__ neg_uv,       // [2][M]
    const float* __restrict__ W2,
    const float* __restrict__ b2,
    float* __restrict__ rowsum, float* __restrict__ colsum, float* __restrict__ pos,
    float* __restrict__ partials,         // [MOTIF_BLOCKS]
    int N, int nb, int M)
{
    __shared__ __align__(16) uchar_t smem[BM*BKF + BN*BKF];   // exactly 32768B

    if (blockIdx.x < MOTIF_BLOCKS) {
        // ---------------- motif path ----------------
        float* wred = (float*)smem;
        int lane = threadIdx.x & 63;
        int sub  = lane >> 3;
        int ch   = (lane & 7) * 8;
        int caseId = blockIdx.x & 7;
        int rank   = (blockIdx.x >> 3) * 4 + (threadIdx.x >> 6);   // 0..1023
        int prod  = caseId >> 1;
        int isneg = caseId & 1;
        const uchar_t* Hu = H + ((size_t)prod*3 + 0)*N*64;
        const uchar_t* Hv = H + ((size_t)prod*3 + 1)*N*64;
        const uchar_t* Hw = H + ((size_t)prod*3 + 2)*N*64;
        const int* iu = isneg ? neg_uv       : motif;
        const int* iv = isneg ? (neg_uv + M) : (motif + M);
        const int* iw = motif + 2*M;

        float w2c[8];
        #pragma unroll
        for (int c = 0; c < 8; ++c) w2c[c] = W2[ch + c];
        float b2v = b2[0];

        float accl = 0.f;
        #pragma unroll 2
        for (int r0 = rank*8; r0 < M; r0 += 8192) {
            int r = r0 + sub;
            bool ok = (r < M);
            int rc = ok ? r : 0;
            int u = iu[rc], v = iv[rc], w = iw[rc];
            uint2 du = *(const uint2*)&Hu[(size_t)u*64 + ch];
            uint2 dv = *(const uint2*)&Hv[(size_t)v*64 + ch];
            uint2 dw = *(const uint2*)&Hw[(size_t)w*64 + ch];
            float pl = 0.f;
            {
                f32x2 s;
                s = pk2<false>(du.x) + pk2<false>(dv.x) + pk2<false>(dw.x);
                pl = fmaf(fmaxf(s.x,0.f), w2c[0], pl);  pl = fmaf(fmaxf(s.y,0.f), w2c[1], pl);
                s = pk2<true>(du.x) + pk2<true>(dv.x) + pk2<true>(dw.x);
                pl = fmaf(fmaxf(s.x,0.f), w2c[2], pl);  pl = fmaf(fmaxf(s.y,0.f), w2c[3], pl);
                s = pk2<false>(du.y) + pk2<false>(dv.y) + pk2<false>(dw.y);
                pl = fmaf(fmaxf(s.x,0.f), w2c[4], pl);  pl = fmaf(fmaxf(s.y,0.f), w2c[5], pl);
                s = pk2<true>(du.y) + pk2<true>(dv.y) + pk2<true>(dw.y);
                pl = fmaf(fmaxf(s.x,0.f), w2c[6], pl);  pl = fmaf(fmaxf(s.y,0.f), w2c[7], pl);
            }
            pl += __shfl_xor(pl, 1, 64);
            pl += __shfl_xor(pl, 2, 64);
            pl += __shfl_xor(pl, 4, 64);
            float logit = pl + b2v;
            float z = isneg ? -logit : logit;
            float sp = fmaxf(-z, 0.f) + __logf(1.f + __expf(-fabsf(z)));
            accl -= ok ? sp : 0.f;
        }
        #pragma unroll
        for (int m = 1; m < 64; m <<= 1) accl += __shfl_xor(accl, m, 64);

        if (lane == 0) wred[threadIdx.x >> 6] = accl;
        __syncthreads();
        if (threadIdx.x == 0)
            partials[blockIdx.x] = (wred[0] + wred[1] + wred[2] + wred[3]) * 0.125f;
        return;
    }

    // ---------------- sim path (r14 single-launch mapping) ----------------
    uchar_t* As = smem;
    uchar_t* Bs = smem + BM*BKF;

    int tid  = threadIdx.x;
    int lane = tid & 63;
    int w    = tid >> 6;
    int wr   = w >> 1, wc = w & 1;
    int quad = lane >> 4, l15 = lane & 15;

    int pid = blockIdx.x - MOTIF_BLOCKS;
    int per_group = 8 * nb;
    int group = pid / per_group;
    int rem = pid - group * per_group;
    int rowspan = min(8, nb - group * 8);
    int prow = group * 8 + rem % rowspan;
    int pcol = rem / rowspan;
    int row0 = prow * BM, col0 = pcol * BN;

    f32x4 acc[4][4];
    #pragma unroll
    for (int i = 0; i < 4; ++i)
        #pragma unroll
        for (int j = 0; j < 4; ++j) acc[i][j] = (f32x4){0.f,0.f,0.f,0.f};

    for (int kt = 0; kt < EMBED; kt += BKF) {
        #pragma unroll
        for (int i = 0; i < 4; ++i) {
            int slot = i*256 + tid;          // slot = row*8 + chunk
            int r = slot >> 3, c = slot & 7;
            int sc = c ^ (r & 7);
            gl2lds16(xn  + (size_t)(row0 + r)*EMBED + kt + sc*16, &As[slot*16]);
            gl2lds16(x2n + (size_t)(col0 + r)*EMBED + kt + sc*16, &Bs[slot*16]);
        }
        __syncthreads();
        #pragma unroll
        for (int s = 0; s < 4; ++s) {        // 4 k-steps of K=32
            long a[4], b[4];
            int g = s*2 + (quad >> 1);
            int sub8 = (quad & 1) * 8;
            #pragma unroll
            for (int ti = 0; ti < 4; ++ti) {
                int ra = wr*64 + ti*16 + l15;
                a[ti] = *(const long*)&As[ra*BKF + (g ^ (ra & 7))*16 + sub8];
            }
            #pragma unroll
            for (int tj = 0; tj < 4; ++tj) {
                int rb = wc*64 + tj*16 + l15;
                b[tj] = *(const long*)&Bs[rb*BKF + (g ^ (rb & 7))*16 + sub8];
            }
            #pragma unroll
            for (int ti = 0; ti < 4; ++ti)
                #pragma unroll
                for (int tj = 0; tj < 4; ++tj)
                    acc[ti][tj] = __builtin_amdgcn_mfma_f32_16x16x32_fp8_fp8(a[ti], b[tj], acc[ti][tj], 0, 0, 0);
        }
        __syncthreads();                     // also: all ds_reads of As/Bs done
    }

    // alias epilogue reduce arrays into As (dead after K-loop)
    float* rsum_s = (float*)smem;
    float* csum_s = rsum_s + BM;
    if (tid < BM) { rsum_s[tid] = 0.f; csum_s[tid] = 0.f; }
    __syncthreads();

    // epilogue: e = exp(acc) (operands pre-scaled by 5), diag, row/col partials
    #pragma unroll
    for (int ti = 0; ti < 4; ++ti) {
        #pragma unroll
        for (int tj = 0; tj < 4; ++tj) {
            #pragma unroll
            for (int r = 0; r < 4; ++r) {
                int gi = row0 + wr*64 + ti*16 + quad*4 + r;
                int gj = col0 + wc*64 + tj*16 + l15;
                float e = 0.f;
                if (gi < N && gj < N) {
                    e = __expf(acc[ti][tj][r]);
                    if (gi == gj) pos[gi] = e;
                }
                acc[ti][tj][r] = e;
            }
        }
    }
    #pragma unroll
    for (int ti = 0; ti < 4; ++ti) {
        #pragma unroll
        for (int r = 0; r < 4; ++r) {
            float rsv = acc[ti][0][r] + acc[ti][1][r] + acc[ti][2][r] + acc[ti][3][r];
            rsv += __shfl_xor(rsv, 1, 64);
            rsv += __shfl_xor(rsv, 2, 64);
            rsv += __shfl_xor(rsv, 4, 64);
            rsv += __shfl_xor(rsv, 8, 64);
            if (l15 == 0) atomicAdd(&rsum_s[wr*64 + ti*16 + quad*4 + r], rsv);
        }
    }
    #pragma unroll
    for (int tj = 0; tj < 4; ++tj) {
        float csv = 0.f;
        #pragma unroll
        for (int ti = 0; ti < 4; ++ti)
            #pragma unroll
            for (int r = 0; r < 4; ++r) csv += acc[ti][tj][r];
        csv += __shfl_xor(csv, 16, 64);
        csv += __shfl_xor(csv, 32, 64);
        if (lane < 16) atomicAdd(&csum_s[wc*64 + tj*16 + lane], csv);
    }
    __syncthreads();
    if (tid < BM) {
        int gi = row0 + tid;
        if (gi < N) atomicAdd(&rowsum[gi], rsum_s[tid]);
        int gj = col0 + tid;
        if (gj < N) atomicAdd(&colsum[gj], csum_s[tid]);
    }
}

// ---------------- Kernel 4a: parallel log-reduction ------------------------
__global__ __launch_bounds__(256) void k_final1(
    const float* __restrict__ rowsum, const float* __restrict__ colsum,
    const float* __restrict__ pos, const float* __restrict__ partials,
    float* __restrict__ acc3, int N, int nparts)
{
    __shared__ float red1[256], red2[256], red3[256];
    int t = threadIdx.x;
    int g = blockIdx.x * 256 + t;
    int stride = gridDim.x * 256;
    float l1 = 0.f, l2 = 0.f, mo = 0.f;
    for (int i = g; i < N; i += stride) {
        float pv = pos[i];
        l1 += __logf((colsum[i] - pv) / pv);
        l2 += __logf((rowsum[i] - pv) / pv);
    }
    for (int i = g; i < nparts; i += stride) mo += partials[i];
    red1[t] = l1; red2[t] = l2; red3[t] = mo; __syncthreads();
    for (int s = 128; s > 0; s >>= 1) {
        if (t < s) { red1[t] += red1[t+s]; red2[t] += red2[t+s]; red3[t] += red3[t+s]; }
        __syncthreads();
    }
    if (t == 0) {
        atomicAdd(&acc3[0], red1[0]);
        atomicAdd(&acc3[1], red2[0]);
        atomicAdd(&acc3[2], red3[0]);
    }
}

// ---------------- Kernel 4b: finalize ---------------------------------------
__global__ void k_final2(const float* __restrict__ acc3,
                         float* __restrict__ out, int N, int M)
{
    if (threadIdx.x == 0) {
        float cl = 0.5f * (acc3[0] + acc3[1]) / (float)N;
        out[0] = cl - acc3[2] / (float)M;
    }
}

extern "C" void kernel_launch(void* const* d_in, const int* in_sizes, int n_in,
                              void* d_out, int out_size, void* d_ws, size_t ws_size,
                              hipStream_t stream)
{
    const float* x         = (const float*)d_in[0];
    const float* feats     = (const float*)d_in[1];
    const float* feat_free = (const float*)d_in[2];
    const float* ks        = (const float*)d_in[3];
    const float* Ws        = (const float*)d_in[4];
    const float* bias      = (const float*)d_in[5];
    const float* W_free    = (const float*)d_in[6];
    const float* b_free    = (const float*)d_in[7];
    const float* W1        = (const float*)d_in[8];
    const float* b1        = (const float*)d_in[9];
    const float* W2        = (const float*)d_in[10];
    const float* b2        = (const float*)d_in[11];
    const int*   motif     = (const int*)d_in[12];
    const int*   neg_uv    = (const int*)d_in[13];
    int N = in_sizes[0] / EMBED;          // 10000
    int M = in_sizes[13] / 2;             // 50000
    int nb = (N + BM - 1) / BM;           // 79
    int Npad = nb * BM;                   // 10112

    uchar_t* xnf8  = (uchar_t*)d_ws;                       // Npad*256 fp8
    uchar_t* x2nf8 = xnf8 + (size_t)Npad*EMBED;            // Npad*256 fp8
    uchar_t* H8    = x2nf8 + (size_t)Npad*EMBED;           // 12*N*64 fp8
    float* p      = (float*)(H8 + (size_t)12*N*64);        // 3*N*32
    float* posv   = p + (size_t)3*N*32;                    // N
    float* rowsum = posv + N;                              // N
    float* colsum = rowsum + N;                            // N
    float* acc3   = colsum + N;                            // 3 (zeroed w/ rowsum/colsum)
    float* partials = acc3 + 3;                            // MOTIF_BLOCKS

    k_embed<<<512, 256, 0, stream>>>(x, feats, feat_free, ks, Ws, bias,
                                     W_free, b_free, p, xnf8, x2nf8,
                                     rowsum, N, Npad);
    k_mlp1<<<1024, 256, 0, stream>>>(p, feat_free, W1, b1, H8, N);
    k_fused<<<MOTIF_BLOCKS + nb*nb, 256, 0, stream>>>(xnf8, x2nf8, H8, motif, neg_uv,
                                                      W2, b2, rowsum, colsum, posv,
                                                      partials, N, nb, M);
    k_final1<<<64, 256, 0, stream>>>(rowsum, colsum, posv, partials, acc3, N, MOTIF_BLOCKS);
    k_final2<<<1, 64, 0, stream>>>(acc3, (float*)d_out, N, M);
}